// Round 1
// baseline (63.894 us; speedup 1.0000x reference)
//
#include <hip/hip_runtime.h>

// 6-qubit circuit simulator, one thread per batch sample.
// State: 64 complex amplitudes held entirely in registers (128 fp32).
// Qubit w (PennyLane wire order: axis w+1 of (B,2,...,2)) maps to bit (5-w)
// of the flat amplitude index.
//
// Gates (all loops fully unrolled; CNOTs are compile-time register swaps):
//   RX(theta): [[c, -i s],[-i s, c]],  c=cos(theta/2), s=sin(theta/2)
//   RY(theta): [[c, -s],[s, c]]
//   CNOT(c,t): swap amplitudes (ctrl=1, tgt=0) <-> (ctrl=1, tgt=1)

#define NQ 6
#define NF 4
#define NL 2
#define NS 64

__global__ __launch_bounds__(256) void qcirc6_kernel(
    const float* __restrict__ x,        // (B, NF)
    const float* __restrict__ weights,  // (NL, NQ)
    const float* __restrict__ bias,     // (2,)
    float* __restrict__ out,            // (B, NF)
    int B)
{
    int i = blockIdx.x * blockDim.x + threadIdx.x;
    if (i >= B) return;

    float4 xv = reinterpret_cast<const float4*>(x)[i];
    float xs[NF] = {xv.x, xv.y, xv.z, xv.w};

    float re[NS], im[NS];
    #pragma unroll
    for (int k = 0; k < NS; ++k) { re[k] = 0.0f; im[k] = 0.0f; }
    re[0] = 1.0f;   // |000000>

    // ---- RX(x[w]) encoding on qubits 0..3 (per-sample angles) ----
    #pragma unroll
    for (int w = 0; w < NF; ++w) {
        float s, c;
        __sincosf(xs[w] * 0.5f, &s, &c);
        const int m = 1 << (5 - w);
        #pragma unroll
        for (int k = 0; k < NS; ++k) {
            if (k & m) continue;
            const int j = k | m;
            const float a0r = re[k], a0i = im[k];
            const float a1r = re[j], a1i = im[j];
            re[k] =  c * a0r + s * a1i;
            im[k] =  c * a0i - s * a1r;
            re[j] =  s * a0i + c * a1r;
            im[j] = -s * a0r + c * a1i;
        }
    }

    // ---- RY(ancilla_bias[q]) on qubits 4,5 ----
    #pragma unroll
    for (int q = 0; q < 2; ++q) {
        float st, ct;
        __sincosf(bias[q] * 0.5f, &st, &ct);
        const int m = 1 << (5 - (4 + q));
        #pragma unroll
        for (int k = 0; k < NS; ++k) {
            if (k & m) continue;
            const int j = k | m;
            const float a0r = re[k], a0i = im[k];
            const float a1r = re[j], a1i = im[j];
            re[k] = ct * a0r - st * a1r;
            im[k] = ct * a0i - st * a1i;
            re[j] = st * a0r + ct * a1r;
            im[j] = st * a0i + ct * a1i;
        }
    }

    // ---- NL layers: CNOT ring then RY(weights[l,w]) on every qubit ----
    #pragma unroll
    for (int l = 0; l < NL; ++l) {
        #pragma unroll
        for (int w = 0; w < NQ; ++w) {
            const int cm = 1 << (5 - w);
            const int tm = 1 << (5 - ((w + 1) % NQ));
            #pragma unroll
            for (int k = 0; k < NS; ++k) {
                if ((k & cm) && !(k & tm)) {
                    const int j = k | tm;
                    float t;
                    t = re[k]; re[k] = re[j]; re[j] = t;
                    t = im[k]; im[k] = im[j]; im[j] = t;
                }
            }
        }
        #pragma unroll
        for (int w = 0; w < NQ; ++w) {
            float st, ct;
            __sincosf(weights[l * NQ + w] * 0.5f, &st, &ct);
            const int m = 1 << (5 - w);
            #pragma unroll
            for (int k = 0; k < NS; ++k) {
                if (k & m) continue;
                const int j = k | m;
                const float a0r = re[k], a0i = im[k];
                const float a1r = re[j], a1i = im[j];
                re[k] = ct * a0r - st * a1r;
                im[k] = ct * a0i - st * a1i;
                re[j] = st * a0r + ct * a1r;
                im[j] = st * a0i + ct * a1i;
            }
        }
    }

    // ---- <Z_w> for w = 0..3 : bit (5-w) of flat index, +1 if 0, -1 if 1 ----
    float z0 = 0.f, z1 = 0.f, z2 = 0.f, z3 = 0.f;
    #pragma unroll
    for (int k = 0; k < NS; ++k) {
        const float p = re[k] * re[k] + im[k] * im[k];
        z0 += (k & 32) ? -p : p;
        z1 += (k & 16) ? -p : p;
        z2 += (k &  8) ? -p : p;
        z3 += (k &  4) ? -p : p;
    }
    reinterpret_cast<float4*>(out)[i] = make_float4(z0, z1, z2, z3);
}

extern "C" void kernel_launch(void* const* d_in, const int* in_sizes, int n_in,
                              void* d_out, int out_size, void* d_ws, size_t ws_size,
                              hipStream_t stream) {
    const float* x       = (const float*)d_in[0];  // (B, 4)
    const float* weights = (const float*)d_in[1];  // (2, 6)
    const float* bias    = (const float*)d_in[2];  // (2,)
    float* out = (float*)d_out;                    // (B, 4)
    const int B = in_sizes[0] / NF;
    qcirc6_kernel<<<(B + 255) / 256, 256, 0, stream>>>(x, weights, bias, out, B);
}